// Round 9
// baseline (73.644 us; speedup 1.0000x reference)
//
#include <hip/hip_runtime.h>
#include <hip/hip_bf16.h>
#include <stdint.h>

typedef float f32x4 __attribute__((ext_vector_type(4)));
typedef short s16x8 __attribute__((ext_vector_type(8)));
typedef unsigned short u16;
typedef u16 u16x4 __attribute__((ext_vector_type(4)));

__device__ __align__(16) float g_tbl[16 * 256]; // 16 units x 64 lanes x f32x4

__device__ __forceinline__ u16 f2bf(float f) {
    union { __hip_bfloat16 h; u16 u; } cv;
    cv.h = __float2bfloat16(f);
    return cv.u;
}
__device__ __forceinline__ int pkbf(float lo, float hi) {
    return (int)(unsigned)f2bf(lo) | ((int)(unsigned)f2bf(hi) << 16);
}
__device__ __forceinline__ f32x4 mfma16(s16x8 a, s16x8 b, f32x4 c) {
    return __builtin_amdgcn_mfma_f32_16x16x32_bf16(a, b, c, 0, 0, 0);
}
__device__ __forceinline__ float exp2_hw(float x) {
    float r; asm("v_exp_f32 %0, %1" : "=v"(r) : "v"(x)); return r;
}
__device__ __forceinline__ int swz16(int v) {                 // lane^16 (verified R4-R8)
    return __builtin_amdgcn_ds_swizzle(v, 0x401F);
}
__device__ __forceinline__ int xor32i(int v, bool lo32) {     // lane^32 (verified R4-R8)
    auto r = __builtin_amdgcn_permlane32_swap(v, v, false, false);
    return lo32 ? r[1] : r[0];
}
__device__ __forceinline__ int pl_lo_to_hi(int v) {           // verified R5-R8
    auto r = __builtin_amdgcn_permlane32_swap(v, v, false, false);
    return r[0];
}
__device__ __forceinline__ s16x8 frag4(int d0, int d1, int d2, int d3) {
    union { int i[4]; s16x8 v; } u;
    u.i[0] = d0; u.i[1] = d1; u.i[2] = d2; u.i[3] = d3;
    return u.v;
}
#define C_FENCE() asm volatile("" ::: "memory")

// ---- one-block setup: per-lane fragment table (proven R8) ----
__global__ void setup_kernel(
    const float* __restrict__ Wq, const float* __restrict__ bq,
    const float* __restrict__ Wk, const float* __restrict__ bk,
    const float* __restrict__ Wv, const float* __restrict__ bv,
    const float* __restrict__ Wo, const float* __restrict__ bo)
{
    const int lane = threadIdx.x & 63;
    if (threadIdx.x >= 64) return;
    const int c16 = lane & 15;
    const int g   = lane >> 4;
    const float qscale = 0.35355339059327373f * 1.4426950408889634f;

    f32x4* T = (f32x4*)g_tbl;
    union { s16x8 s; f32x4 f; } cv;
    #pragma unroll
    for (int j = 0; j < 6; ++j) {
        const float* Wsrc = (j < 2) ? Wq : (j < 4) ? Wk : Wv;
        const int colW = ((j & 1) << 4) | c16;
        const float sc = (j < 2) ? qscale : 1.0f;
        s16x8 wf;
        #pragma unroll
        for (int jj = 0; jj < 8; ++jj)
            wf[jj] = (short)f2bf(Wsrc[(g * 8 + jj) * 32 + colW] * sc);
        cv.s = wf;
        T[j * 64 + lane] = cv.f;
    }
    #pragma unroll
    for (int j2 = 0; j2 < 2; ++j2) {
        const int cout = j2 * 16 + c16;
        s16x8 wf;
        #pragma unroll
        for (int jj = 0; jj < 8; ++jj) {
            const int h = (g >> 1) * 2 + (jj >> 2);
            const int d = 4 * (g & 1) + (jj & 3);
            wf[jj] = (short)f2bf(Wo[(h * 8 + d) * 32 + cout]);
        }
        cv.s = wf;
        T[(6 + j2) * 64 + lane] = cv.f;
    }
    #pragma unroll
    for (int j = 0; j < 4; ++j) {
        const float* bsrc = (j < 2) ? bq : bk;
        const float sc = (j < 2) ? qscale : 1.0f;
        f32x4 b;
        #pragma unroll
        for (int i = 0; i < 4; ++i)
            b[i] = bsrc[((j & 1) << 4) + 4 * g + i] * sc;
        T[(8 + j) * 64 + lane] = b;
    }
    #pragma unroll
    for (int jv = 0; jv < 2; ++jv) {
        float b = bv[jv * 16 + c16];
        T[(12 + jv) * 64 + lane] = (f32x4){b, b, b, b};
    }
    #pragma unroll
    for (int j2 = 0; j2 < 2; ++j2) {
        f32x4 b;
        #pragma unroll
        for (int i = 0; i < 4; ++i)
            b[i] = bo[j2 * 16 + 4 * g + i];
        T[(14 + j2) * 64 + lane] = b;
    }
}

// 1 wave = 2 windows IN FLIGHT (independent chains), 2 pair-iterations = 4 windows.
__global__ __launch_bounds__(256) void swin_attn_kernel(
    const float* __restrict__ x, float* __restrict__ out)
{
    const int lane  = threadIdx.x & 63;
    const int wave  = threadIdx.x >> 6;
    const int c16   = lane & 15;
    const int g     = lane >> 4;
    const bool lo32 = (lane < 32);

    // two window slots (par 0/1), R7 zero-pad layout per slot
    __shared__ __align__(16) u16 qk[2][4][16][88];
    __shared__ __align__(16) u16 vT[2][4][33][24];
    __shared__ __align__(16) u16 pB[2][4][17][24];

    // ---- zero-init pads (both slots) ----
    #pragma unroll
    for (int par = 0; par < 2; ++par) {
        const int col = (g < 2) ? (32 + 4 * g) : (72 + 4 * (g - 2));
        *(u16x4*)&qk[par][wave][c16][col] = (u16x4){0, 0, 0, 0};
        if (lane < 6) *(u16x4*)&vT[par][wave][32][lane * 4] = (u16x4){0, 0, 0, 0};
        if (lane < 6) *(u16x4*)&pB[par][wave][16][lane * 4] = (u16x4){0, 0, 0, 0};
    }
    C_FENCE();

    // ---- prologue: 16 coalesced loads from fragment table (proven R8) ----
    const f32x4* T = (const f32x4*)g_tbl;
    f32x4 u[16];
    #pragma unroll
    for (int k = 0; k < 16; ++k) u[k] = T[k * 64 + lane];
    union { f32x4 f; s16x8 s; } cv;
    s16x8 wqkv[6], wo_frag[2];
    #pragma unroll
    for (int j = 0; j < 6; ++j) { cv.f = u[j]; wqkv[j] = cv.s; }
    cv.f = u[6]; wo_frag[0] = cv.s;
    cv.f = u[7]; wo_frag[1] = cv.s;
    f32x4 bias_qk[4] = {u[8], u[9], u[10], u[11]};
    f32x4 bias_v[2]  = {u[12], u[13]};
    f32x4 bo_frag[2] = {u[14], u[15]};

    const f32x4 zero4 = {0.f, 0.f, 0.f, 0.f};

    // per-slot hoisted fragment pointers (R7 pattern)
    const int hstep = (g == 0) ? 8 : 0;
    const int vstep = (g < 2) ? 8 * 24 : 0;
    const u16 *ap[2], *bp[2], *pp[2], *vp[2];
    #pragma unroll
    for (int par = 0; par < 2; ++par) {
        ap[par] = (g == 0) ? &qk[par][wave][c16][40] : &qk[par][wave][c16][72];
        bp[par] = (g == 0) ? &qk[par][wave][c16][0]  : &qk[par][wave][c16][32];
        pp[par] = (g < 2) ? &pB[par][wave][c16][g * 8] : &pB[par][wave][16][0];
        vp[par] = (g < 2) ? &vT[par][wave][c16 & 7][g * 8] : &vT[par][wave][32][0];
    }

    const int wbase = (blockIdx.x * 4 + wave) * 4;
    auto pixaddr = [&](int w) -> long {
        const int b = w >> 14, rem = w & 16383, wi = rem >> 7, wj = rem & 127;
        const int row  = (wi * 4 + (c16 >> 2) + 2) & 511;
        const int colp = (wj * 4 + (c16 & 3) + 2) & 511;
        return ((((long)b << 9) + row) * 512 + colp) * 32;
    };

    // prologue: load both windows of pair 0
    long pixA = pixaddr(wbase), pixB = pixaddr(wbase + 1);
    f32x4 pxA0 = *(const f32x4*)(x + pixA + g * 8);
    f32x4 pxA1 = *(const f32x4*)(x + pixA + g * 8 + 4);
    f32x4 pxB0 = *(const f32x4*)(x + pixB + g * 8);
    f32x4 pxB1 = *(const f32x4*)(x + pixB + g * 8 + 4);

    #pragma unroll 1
    for (int kk = 0; kk < 2; ++kk) {
        const long pbA = pixA, pbB = pixB;
        s16x8 xfA = frag4(pkbf(pxA0[0], pxA0[1]), pkbf(pxA0[2], pxA0[3]),
                          pkbf(pxA1[0], pxA1[1]), pkbf(pxA1[2], pxA1[3]));
        s16x8 xfB = frag4(pkbf(pxB0[0], pxB0[1]), pkbf(pxB0[2], pxB0[3]),
                          pkbf(pxB1[0], pxB1[1]), pkbf(pxB1[2], pxB1[3]));

        // ---- phase A: projections -> LDS staging, both slots ----
        #pragma unroll
        for (int j = 0; j < 4; ++j) {
            f32x4 cA = mfma16(wqkv[j], xfA, bias_qk[j]);
            f32x4 cB = mfma16(wqkv[j], xfB, bias_qk[j]);
            const int col = (j < 2) ? (j * 16 + 4 * g) : (40 + (j - 2) * 16 + 4 * g);
            u16x4 qa, qb;
            #pragma unroll
            for (int i = 0; i < 4; ++i) { qa[i] = f2bf(cA[i]); qb[i] = f2bf(cB[i]); }
            *(u16x4*)&qk[0][wave][c16][col] = qa;
            *(u16x4*)&qk[1][wave][c16][col] = qb;
        }
        #pragma unroll
        for (int jv = 0; jv < 2; ++jv) {
            f32x4 cA = mfma16(xfA, wqkv[4 + jv], bias_v[jv]);
            f32x4 cB = mfma16(xfB, wqkv[4 + jv], bias_v[jv]);
            u16x4 va, vb;
            #pragma unroll
            for (int i = 0; i < 4; ++i) { va[i] = f2bf(cA[i]); vb[i] = f2bf(cB[i]); }
            *(u16x4*)&vT[0][wave][jv * 16 + c16][4 * g] = va;
            *(u16x4*)&vT[1][wave][jv * 16 + c16][4 * g] = vb;
        }

        // prefetch next pair (wrap at kk==1: harmless re-read)
        {
            const int nA = wbase + ((2 * kk + 2) & 3);
            const int nB = wbase + ((2 * kk + 3) & 3);
            pixA = pixaddr(nA); pixB = pixaddr(nB);
            pxA0 = *(const f32x4*)(x + pixA + g * 8);
            pxA1 = *(const f32x4*)(x + pixA + g * 8 + 4);
            pxB0 = *(const f32x4*)(x + pixB + g * 8);
            pxB1 = *(const f32x4*)(x + pixB + g * 8 + 4);
        }
        f32x4 rA0 = *(const f32x4*)(x + pbA + 4 * g);
        f32x4 rA1 = *(const f32x4*)(x + pbA + 16 + 4 * g);
        f32x4 rB0 = *(const f32x4*)(x + pbB + 4 * g);
        f32x4 rB1 = *(const f32x4*)(x + pbB + 16 + 4 * g);

        C_FENCE(); // staging -> fragment reads

        // ---- phase B: heads, two independent chains interleaved ----
        f32x4 oA[4], oB[4];
        #pragma unroll
        for (int h = 0; h < 4; ++h) {
            s16x8 afA = *(const s16x8*)(ap[0] + h * hstep);
            s16x8 bfA = *(const s16x8*)(bp[0] + h * hstep);
            s16x8 afB = *(const s16x8*)(ap[1] + h * hstep);
            s16x8 bfB = *(const s16x8*)(bp[1] + h * hstep);
            f32x4 sA = mfma16(afA, bfA, zero4);
            f32x4 sB = mfma16(afB, bfB, zero4);

            float a0 = exp2_hw(sA[0]), a1 = exp2_hw(sA[1]);
            float a2 = exp2_hw(sA[2]), a3 = exp2_hw(sA[3]);
            float b0 = exp2_hw(sB[0]), b1 = exp2_hw(sB[1]);
            float b2 = exp2_hw(sB[2]), b3 = exp2_hw(sB[3]);
            float partA = (a0 + a1) + (a2 + a3);
            float partB = (b0 + b1) + (b2 + b3);
            float sumA = partA + __int_as_float(swz16(__float_as_int(partA)));
            float sumB = partB + __int_as_float(swz16(__float_as_int(partB)));
            sumA += __int_as_float(xor32i(__float_as_int(sumA), lo32));
            sumB += __int_as_float(xor32i(__float_as_int(sumB), lo32));
            const float invA = __builtin_amdgcn_rcpf(sumA);
            const float invB = __builtin_amdgcn_rcpf(sumB);
            u16x4 pa, pb;
            pa[0] = f2bf(a0 * invA); pa[1] = f2bf(a1 * invA);
            pa[2] = f2bf(a2 * invA); pa[3] = f2bf(a3 * invA);
            pb[0] = f2bf(b0 * invB); pb[1] = f2bf(b1 * invB);
            pb[2] = f2bf(b2 * invB); pb[3] = f2bf(b3 * invB);
            *(u16x4*)&pB[0][wave][c16][4 * g] = pa;
            *(u16x4*)&pB[1][wave][c16][4 * g] = pb;
            C_FENCE(); // P writes -> P reads

            s16x8 vfA = *(const s16x8*)(vp[0] + h * vstep);
            s16x8 pfA = *(const s16x8*)pp[0];
            s16x8 vfB = *(const s16x8*)(vp[1] + h * vstep);
            s16x8 pfB = *(const s16x8*)pp[1];
            oA[h] = mfma16(vfA, pfA, zero4);
            oB[h] = mfma16(vfB, pfB, zero4);
            C_FENCE(); // P reads before next head's P writes
        }

        // ---- phase C + epilogue, slot A ----
        {
            int t00 = pkbf(oA[0][0], oA[0][1]), t01 = pkbf(oA[0][2], oA[0][3]);
            int t10 = pkbf(oA[1][0], oA[1][1]), t11 = pkbf(oA[1][2], oA[1][3]);
            int t20 = pkbf(oA[2][0], oA[2][1]), t21 = pkbf(oA[2][2], oA[2][3]);
            int t30 = pkbf(oA[3][0], oA[3][1]), t31 = pkbf(oA[3][2], oA[3][3]);
            int m20 = pl_lo_to_hi(t20), m21 = pl_lo_to_hi(t21);
            int m30 = pl_lo_to_hi(t30), m31 = pl_lo_to_hi(t31);
            s16x8 ofrag = frag4(lo32 ? t00 : m20, lo32 ? t01 : m21,
                                lo32 ? t10 : m30, lo32 ? t11 : m31);
            f32x4 ci0 = bo_frag[0], ci1 = bo_frag[1];
            #pragma unroll
            for (int i = 0; i < 4; ++i) { ci0[i] += rA0[i]; ci1[i] += rA1[i]; }
            f32x4 c0 = mfma16(wo_frag[0], ofrag, ci0);
            f32x4 c1 = mfma16(wo_frag[1], ofrag, ci1);
            *(f32x4*)(out + pbA + 4 * g) = c0;
            *(f32x4*)(out + pbA + 16 + 4 * g) = c1;
        }
        // ---- phase C + epilogue, slot B ----
        {
            int t00 = pkbf(oB[0][0], oB[0][1]), t01 = pkbf(oB[0][2], oB[0][3]);
            int t10 = pkbf(oB[1][0], oB[1][1]), t11 = pkbf(oB[1][2], oB[1][3]);
            int t20 = pkbf(oB[2][0], oB[2][1]), t21 = pkbf(oB[2][2], oB[2][3]);
            int t30 = pkbf(oB[3][0], oB[3][1]), t31 = pkbf(oB[3][2], oB[3][3]);
            int m20 = pl_lo_to_hi(t20), m21 = pl_lo_to_hi(t21);
            int m30 = pl_lo_to_hi(t30), m31 = pl_lo_to_hi(t31);
            s16x8 ofrag = frag4(lo32 ? t00 : m20, lo32 ? t01 : m21,
                                lo32 ? t10 : m30, lo32 ? t11 : m31);
            f32x4 ci0 = bo_frag[0], ci1 = bo_frag[1];
            #pragma unroll
            for (int i = 0; i < 4; ++i) { ci0[i] += rB0[i]; ci1[i] += rB1[i]; }
            f32x4 c0 = mfma16(wo_frag[0], ofrag, ci0);
            f32x4 c1 = mfma16(wo_frag[1], ofrag, ci1);
            *(f32x4*)(out + pbB + 4 * g) = c0;
            *(f32x4*)(out + pbB + 16 + 4 * g) = c1;
        }

        C_FENCE(); // next pair's staging after this pair's reads
    }
}

extern "C" void kernel_launch(void* const* d_in, const int* in_sizes, int n_in,
                              void* d_out, int out_size, void* d_ws, size_t ws_size,
                              hipStream_t stream) {
    const float* x  = (const float*)d_in[0];
    const float* Wq = (const float*)d_in[1];
    const float* bq = (const float*)d_in[2];
    const float* Wk = (const float*)d_in[3];
    const float* bk = (const float*)d_in[4];
    const float* Wv = (const float*)d_in[5];
    const float* bv = (const float*)d_in[6];
    const float* Wo = (const float*)d_in[7];
    const float* bo = (const float*)d_in[8];
    float* out = (float*)d_out;

    hipLaunchKernelGGL(setup_kernel, dim3(1), dim3(64), 0, stream,
                       Wq, bq, Wk, bk, Wv, bv, Wo, bo);
    hipLaunchKernelGGL(swin_attn_kernel, dim3(4096), dim3(256), 0, stream,
                       x, out);
}